// Round 8
// baseline (1597.376 us; speedup 1.0000x reference)
//
#include <hip/hip_runtime.h>
#include <hip/hip_bf16.h>
#include <math.h>

#define NB 8192
#define NHID 256

typedef __attribute__((ext_vector_type(8))) short short8;
typedef __attribute__((ext_vector_type(4))) float f32x4;
typedef unsigned short u16;

typedef __attribute__((address_space(3))) unsigned char* as3_u8;
typedef const __attribute__((address_space(1))) unsigned char* as1_cu8;
#define GLOAD_LDS16(g, l) \
    __builtin_amdgcn_global_load_lds((as1_cu8)(g), (as3_u8)(l), 16, 0, 0)

__device__ __forceinline__ void split1(float f, u16& h, u16& l) {
    __hip_bfloat16 hb = __float2bfloat16(f);
    float fh = __bfloat162float(hb);
    __hip_bfloat16 lb = __float2bfloat16(f - fh);
    h = *(u16*)&hb; l = *(u16*)&lb;
}

__device__ __forceinline__ bool better(float a, int ia, float b, int ib) {
    return (a > b) || (a == b && ia < ib);
}

// sorted-descending top-8 insert; all indices compile-time after unroll
__device__ __forceinline__ void ins8(float v, int ix, float (&tv)[8], int (&ti)[8]) {
    if (better(v, ix, tv[7], ti[7])) {
        tv[7] = v; ti[7] = ix;
#pragma unroll
        for (int s = 7; s > 0; s--) {
            if (better(tv[s], ti[s], tv[s - 1], ti[s - 1])) {
                float tf = tv[s]; tv[s] = tv[s - 1]; tv[s - 1] = tf;
                int   tt = ti[s]; ti[s] = ti[s - 1]; ti[s - 1] = tt;
            }
        }
    }
}

// =====================================================================
// K0: wconv — transpose + bf16 hi/lo split of Wp0/1/2 and Win.
// =====================================================================
__global__ __launch_bounds__(256) void wconv_kernel(
    const float* __restrict__ Wp0, const float* __restrict__ Wp1,
    const float* __restrict__ Wp2, const float* __restrict__ Win,
    u16* __restrict__ WTh, u16* __restrict__ WTl,
    u16* __restrict__ WinTh, u16* __restrict__ WinTl)
{
    __shared__ float Ts[32][33];
    const int b = blockIdx.x;
    const int tid = threadIdx.x;
    const float* src; u16 *dh, *dl; int W, outstride, outbase, k0, c0;
    if (b < 576) {
        int base, koff;
        const float* wp;
        if (b < 128)      { base = 0;   koff = 0;    wp = Wp0; }
        else if (b < 320) { base = 128; koff = 512;  wp = Wp1; }
        else              { base = 320; koff = 1280; wp = Wp2; }
        int lb = b - base;
        k0 = (lb >> 3) * 32; c0 = (lb & 7) * 32;
        src = wp; W = 256; dh = WTh; dl = WTl; outstride = 2304; outbase = koff;
    } else {
        int lb = b - 576;
        k0 = (lb & 7) * 32; c0 = (lb >> 3) * 32;
        src = Win; W = 768; dh = WinTh; dl = WinTl; outstride = 256; outbase = 0;
    }
    {
        int r = tid >> 3, cq = (tid & 7) * 4;
        float4 v = *(const float4*)&src[(size_t)(k0 + r) * W + c0 + cq];
        Ts[r][cq] = v.x; Ts[r][cq + 1] = v.y; Ts[r][cq + 2] = v.z; Ts[r][cq + 3] = v.w;
    }
    __syncthreads();
    {
        int c = tid >> 3, r4 = (tid & 7) * 4;
        ushort4 h, l;
        split1(Ts[r4 + 0][c], h.x, l.x);
        split1(Ts[r4 + 1][c], h.y, l.y);
        split1(Ts[r4 + 2][c], h.z, l.z);
        split1(Ts[r4 + 3][c], h.w, l.w);
        size_t off = (size_t)(c0 + c) * outstride + outbase + k0 + r4;
        *(ushort4*)&dh[off] = h;
        *(ushort4*)&dl[off] = l;
    }
}

// =====================================================================
// K1: proj_mfma — Linear -> ReLU -> LayerNorm via 3-term bf16-split MFMA
// =====================================================================
__global__ __launch_bounds__(256) void proj_mfma_kernel(
    const float* __restrict__ x0, const float* __restrict__ x1, const float* __restrict__ x2,
    const float* __restrict__ bp0, const float* __restrict__ g0, const float* __restrict__ be0,
    const float* __restrict__ bp1, const float* __restrict__ g1, const float* __restrict__ be1,
    const float* __restrict__ bp2, const float* __restrict__ g2, const float* __restrict__ be2,
    const u16* __restrict__ WTh, const u16* __restrict__ WTl,
    u16* __restrict__ seqh, u16* __restrict__ seql)
{
    __shared__ __align__(16) unsigned char smem[51200];

    const int m = blockIdx.y;
    const float* x; const float* bp; const float* g; const float* be; int d, koff;
    if (m == 0)      { x = x0; bp = bp0; g = g0; be = be0; d = 512;  koff = 0; }
    else if (m == 1) { x = x1; bp = bp1; g = g1; be = be1; d = 768;  koff = 512; }
    else             { x = x2; bp = bp2; g = g2; be = be2; d = 1024; koff = 1280; }

    const int tid = threadIdx.x;
    const int lane = tid & 63;
    const int w  = tid >> 6;
    const int lr = lane & 15;
    const int lg = lane >> 4;
    const int r0 = blockIdx.x * 64;

    f32x4 acc[16];
#pragma unroll
    for (int nf = 0; nf < 16; nf++) acc[nf] = (f32x4)0.f;

    const int nkt = d >> 5;
    for (int kt = 0; kt < nkt; kt++) {
        const int k0 = kt << 5;
        __syncthreads();
#pragma unroll
        for (int i = 0; i < 4; i++) {
            int id = i * 256 + tid;
            int col = id >> 2, ks = (id & 3) * 8;
            size_t go = (size_t)col * 2304 + koff + k0 + ks;
            *(short8*)(smem + col * 80 + ks * 2)         = *(const short8*)&WTh[go];
            *(short8*)(smem + 20480 + col * 80 + ks * 2) = *(const short8*)&WTl[go];
        }
#pragma unroll
        for (int i = 0; i < 2; i++) {
            int id = i * 256 + tid;
            int row = id >> 3, kq = (id & 7) * 4;
            float4 v = *(const float4*)&x[(size_t)(r0 + row) * d + k0 + kq];
            ushort4 h, l;
            split1(v.x, h.x, l.x); split1(v.y, h.y, l.y);
            split1(v.z, h.z, l.z); split1(v.w, h.w, l.w);
            *(ushort4*)(smem + 40960 + row * 80 + kq * 2) = h;
            *(ushort4*)(smem + 46080 + row * 80 + kq * 2) = l;
        }
        __syncthreads();

        short8 bvh = *(const short8*)(smem + 40960 + (w * 16 + lr) * 80 + lg * 16);
        short8 bvl = *(const short8*)(smem + 46080 + (w * 16 + lr) * 80 + lg * 16);
#pragma unroll
        for (int nf = 0; nf < 16; nf++) {
            short8 avh = *(const short8*)(smem + (nf * 16 + lr) * 80 + lg * 16);
            short8 avl = *(const short8*)(smem + 20480 + (nf * 16 + lr) * 80 + lg * 16);
            acc[nf] = __builtin_amdgcn_mfma_f32_16x16x32_bf16(avh, bvh, acc[nf], 0, 0, 0);
            acc[nf] = __builtin_amdgcn_mfma_f32_16x16x32_bf16(avl, bvh, acc[nf], 0, 0, 0);
            acc[nf] = __builtin_amdgcn_mfma_f32_16x16x32_bf16(avh, bvl, acc[nf], 0, 0, 0);
        }
    }

    float s = 0.f, s2 = 0.f;
#pragma unroll
    for (int nf = 0; nf < 16; nf++) {
        float4 bpv = *(const float4*)&bp[nf * 16 + lg * 4];
        float bb[4] = {bpv.x, bpv.y, bpv.z, bpv.w};
#pragma unroll
        for (int r = 0; r < 4; r++) {
            float y = fmaxf(acc[nf][r] + bb[r], 0.f);
            acc[nf][r] = y;
            s += y; s2 += y * y;
        }
    }
    s  += __shfl_xor(s, 16);  s  += __shfl_xor(s, 32);
    s2 += __shfl_xor(s2, 16); s2 += __shfl_xor(s2, 32);
    const float meanv = s * (1.f / 256.f);
    const float inv = 1.f / sqrtf(s2 * (1.f / 256.f) - meanv * meanv + 1e-5f);

    const size_t rb = ((size_t)(r0 + w * 16 + lr) * 3 + m) * 256;
#pragma unroll
    for (int nf = 0; nf < 16; nf++) {
        float4 gv  = *(const float4*)&g[nf * 16 + lg * 4];
        float4 bev = *(const float4*)&be[nf * 16 + lg * 4];
        float gc[4] = {gv.x, gv.y, gv.z, gv.w};
        float bc[4] = {bev.x, bev.y, bev.z, bev.w};
        ushort4 h, l;
        float o0 = (acc[nf][0] - meanv) * inv * gc[0] + bc[0];
        float o1 = (acc[nf][1] - meanv) * inv * gc[1] + bc[1];
        float o2 = (acc[nf][2] - meanv) * inv * gc[2] + bc[2];
        float o3 = (acc[nf][3] - meanv) * inv * gc[3] + bc[3];
        split1(o0, h.x, l.x); split1(o1, h.y, l.y);
        split1(o2, h.z, l.z); split1(o3, h.w, l.w);
        *(ushort4*)&seqh[rb + nf * 16 + lg * 4] = h;
        *(ushort4*)&seql[rb + nf * 16 + lg * 4] = l;
    }
}

// =====================================================================
// K2: qkv_mfma — qkv = seq @ Win + bin via 3-term bf16-split MFMA.
// =====================================================================
__global__ __launch_bounds__(256) void qkv_mfma_kernel(
    const u16* __restrict__ seqh, const u16* __restrict__ seql,
    const u16* __restrict__ WinTh, const u16* __restrict__ WinTl,
    const float* __restrict__ bin, float* __restrict__ qkv)
{
    __shared__ __align__(16) unsigned char smem[51200];
    const int tid = threadIdx.x;
    const int lane = tid & 63;
    const int w  = tid >> 6;
    const int lr = lane & 15;
    const int lg = lane >> 4;
    const int c0 = blockIdx.x << 8;
    const int r0 = blockIdx.y << 6;

    f32x4 acc[16];
#pragma unroll
    for (int nf = 0; nf < 16; nf++) acc[nf] = (f32x4)0.f;

    for (int kt = 0; kt < 8; kt++) {
        const int k0 = kt << 5;
        __syncthreads();
#pragma unroll
        for (int i = 0; i < 4; i++) {
            int id = i * 256 + tid;
            int col = id >> 2, ks = (id & 3) * 8;
            size_t go = (size_t)(c0 + col) * 256 + k0 + ks;
            *(short8*)(smem + col * 80 + ks * 2)         = *(const short8*)&WinTh[go];
            *(short8*)(smem + 20480 + col * 80 + ks * 2) = *(const short8*)&WinTl[go];
        }
        {
            int row = tid >> 2, ks = (tid & 3) * 8;
            size_t go = (size_t)(r0 + row) * 256 + k0 + ks;
            *(short8*)(smem + 40960 + row * 80 + ks * 2) = *(const short8*)&seqh[go];
            *(short8*)(smem + 46080 + row * 80 + ks * 2) = *(const short8*)&seql[go];
        }
        __syncthreads();

        short8 bvh = *(const short8*)(smem + 40960 + (w * 16 + lr) * 80 + lg * 16);
        short8 bvl = *(const short8*)(smem + 46080 + (w * 16 + lr) * 80 + lg * 16);
#pragma unroll
        for (int nf = 0; nf < 16; nf++) {
            short8 avh = *(const short8*)(smem + (nf * 16 + lr) * 80 + lg * 16);
            short8 avl = *(const short8*)(smem + 20480 + (nf * 16 + lr) * 80 + lg * 16);
            acc[nf] = __builtin_amdgcn_mfma_f32_16x16x32_bf16(avh, bvh, acc[nf], 0, 0, 0);
            acc[nf] = __builtin_amdgcn_mfma_f32_16x16x32_bf16(avl, bvh, acc[nf], 0, 0, 0);
            acc[nf] = __builtin_amdgcn_mfma_f32_16x16x32_bf16(avh, bvl, acc[nf], 0, 0, 0);
        }
    }

    const size_t rb = (size_t)(r0 + w * 16 + lr) * 768 + c0;
#pragma unroll
    for (int nf = 0; nf < 16; nf++) {
        float4 bv = *(const float4*)&bin[c0 + nf * 16 + lg * 4];
        float4 o = make_float4(acc[nf][0] + bv.x, acc[nf][1] + bv.y,
                               acc[nf][2] + bv.z, acc[nf][3] + bv.w);
        *(float4*)&qkv[rb + nf * 16 + lg * 4] = o;
    }
}

// =====================================================================
// K3: attention + out-proj + mean + edge MLP; writes Fh/Fl (bf16 split)
// =====================================================================
__global__ __launch_bounds__(256) void attn_kernel(
    const float* __restrict__ qkv, const float* __restrict__ Wout,
    const float* __restrict__ bout, const float* __restrict__ W1,
    const float* __restrict__ b1, const float* __restrict__ W2,
    const float* __restrict__ b2, u16* __restrict__ Fh, u16* __restrict__ Fl,
    float* __restrict__ ew)
{
    __shared__ float qk[4][2304];
    __shared__ float at[4][4][3][3];
    __shared__ float ol[12][256];
    __shared__ float fl[4][256];
    __shared__ float h1[4][128];

    const int tid = threadIdx.x;
    const int b0 = blockIdx.x * 4;

#pragma unroll
    for (int i = 0; i < 9; i++) {
        int f4 = i * 256 + tid;
        int lb = f4 / 576, rem = f4 - lb * 576;
        *(float4*)&qk[lb][rem * 4] =
            *(const float4*)&qkv[(size_t)(b0 + lb) * 2304 + rem * 4];
    }
    __syncthreads();

    if (tid < 144) {
        int lb = tid / 36, r = tid % 36;
        int h = r / 9, s = (r / 3) % 3, t = r % 3;
        const float* qp = &qk[lb][s * 768 + h * 64];
        const float* kp = &qk[lb][t * 768 + 256 + h * 64];
        float sum = 0.f;
#pragma unroll
        for (int dd = 0; dd < 64; dd++) sum = fmaf(qp[dd], kp[dd], sum);
        at[lb][h][s][t] = sum * 0.125f;
    }
    __syncthreads();

    if (tid < 48) {
        int lb = tid / 12, h = (tid / 3) % 4, s = tid % 3;
        float v0 = at[lb][h][s][0], v1 = at[lb][h][s][1], v2 = at[lb][h][s][2];
        float mx = fmaxf(v0, fmaxf(v1, v2));
        float e0 = expf(v0 - mx), e1 = expf(v1 - mx), e2 = expf(v2 - mx);
        float inv = 1.f / (e0 + e1 + e2);
        at[lb][h][s][0] = e0 * inv; at[lb][h][s][1] = e1 * inv; at[lb][h][s][2] = e2 * inv;
    }
    __syncthreads();

    {
        int j = tid, h = j >> 6;
#pragma unroll
        for (int lb = 0; lb < 4; lb++)
#pragma unroll
            for (int s = 0; s < 3; s++) {
                float o = at[lb][h][s][0] * qk[lb][0 * 768 + 512 + j]
                        + at[lb][h][s][1] * qk[lb][1 * 768 + 512 + j]
                        + at[lb][h][s][2] * qk[lb][2 * 768 + 512 + j];
                ol[lb * 3 + s][j] = o;
            }
    }
    __syncthreads();

    {
        const int txx = tid & 63, lbb = tid >> 6;
        float a0[4] = {0, 0, 0, 0}, a1[4] = {0, 0, 0, 0}, a2[4] = {0, 0, 0, 0};
        for (int k = 0; k < 256; k++) {
            float4 w = *(const float4*)&Wout[(size_t)k * 256 + txx * 4];
            float wv[4] = {w.x, w.y, w.z, w.w};
            float o0 = ol[lbb * 3 + 0][k], o1 = ol[lbb * 3 + 1][k], o2 = ol[lbb * 3 + 2][k];
#pragma unroll
            for (int c = 0; c < 4; c++) {
                a0[c] = fmaf(o0, wv[c], a0[c]);
                a1[c] = fmaf(o1, wv[c], a1[c]);
                a2[c] = fmaf(o2, wv[c], a2[c]);
            }
        }
        float4 bo = *(const float4*)&bout[txx * 4];
        float bc[4] = {bo.x, bo.y, bo.z, bo.w};
        float f[4];
        u16 hq[4], lq[4];
#pragma unroll
        for (int c = 0; c < 4; c++) {
            f[c] = ((a0[c] + bc[c]) + (a1[c] + bc[c]) + (a2[c] + bc[c])) * (1.f / 3.f);
            split1(f[c], hq[c], lq[c]);
        }
        *(float4*)&fl[lbb][txx * 4] = make_float4(f[0], f[1], f[2], f[3]);
        uint2 hp, lp;
        hp.x = (unsigned)hq[0] | ((unsigned)hq[1] << 16);
        hp.y = (unsigned)hq[2] | ((unsigned)hq[3] << 16);
        lp.x = (unsigned)lq[0] | ((unsigned)lq[1] << 16);
        lp.y = (unsigned)lq[2] | ((unsigned)lq[3] << 16);
        *(uint2*)&Fh[(size_t)(b0 + lbb) * NHID + txx * 4] = hp;
        *(uint2*)&Fl[(size_t)(b0 + lbb) * NHID + txx * 4] = lp;
    }
    __syncthreads();

    {
        int lb = tid >> 6, j = tid & 63;
        float s0 = 0.f, s1 = 0.f;
        for (int k = 0; k < 256; k++) {
            float fv = fl[lb][k];
            s0 = fmaf(fv, W1[(size_t)k * 128 + j], s0);
            s1 = fmaf(fv, W1[(size_t)k * 128 + j + 64], s1);
        }
        h1[lb][j]      = fmaxf(s0 + b1[j], 0.f);
        h1[lb][j + 64] = fmaxf(s1 + b1[j + 64], 0.f);
    }
    __syncthreads();
    if (tid < 4) {
        float s = 0.f;
        for (int j = 0; j < 128; j++) s = fmaf(h1[tid][j], W2[j], s);
        s += b2[0];
        float e = 1.f / (1.f + expf(-s));
        ew[b0 + tid] = fmaxf(e, 1e-8f);
    }
}

// =====================================================================
// K4: FUSED sim + topk: logits never hit HBM.
// Grid 512 = 64 rowblks(128 rows) x 8 col-splits(1024 cols).
// Per 64-col tile: 12-kt 3-term bf16-split MFMA (identical arithmetic to
// the verified sim kernel -> identical selection), dump C tile to LDS,
// 2 threads/row merge into persistent reg top-8 + online (m,l) sumexp.
// Epilogue: pair-merge via shfl, write per-(row,split) records.
// =====================================================================
__global__ __launch_bounds__(256) void fused_sim_topk_kernel(
    const u16* __restrict__ Fh, const u16* __restrict__ Fl,
    float* __restrict__ Ml, float* __restrict__ Vsp, int* __restrict__ Isp)
{
    // As: [0,16384) 128 rows x 128B ; Bs: [16384,24576) 64 x 128B
    // Cs: [24576,59392) 128 x 68 floats
    __shared__ __align__(16) unsigned char smem[59392];
    float* Cs = (float*)(smem + 24576);

    const int tid  = threadIdx.x;
    const int lane = tid & 63;
    const int w    = tid >> 6;
    const int lr   = lane & 15;
    const int lg   = lane >> 4;
    const int rowblk = blockIdx.x >> 3;
    const int split  = blockIdx.x & 7;
    const int i0 = rowblk << 7;
    const int j0 = split << 10;

    const int srow = lane >> 3;
    const int acol = ((lane & 7) ^ srow) * 8;

    const int mrow = tid >> 1;       // merge: row ownership (0..127)
    const int mhalf = tid & 1;       // which 32-col half

    float tv[8]; int ti[8];
#pragma unroll
    for (int s = 0; s < 8; s++) { tv[s] = -INFINITY; ti[s] = 0x7fffffff; }
    float rm = -INFINITY, rl = 0.f;

    for (int t = 0; t < 16; t++) {
        const int jt = j0 + (t << 6);
        f32x4 acc[4][2];
#pragma unroll
        for (int a = 0; a < 4; a++)
#pragma unroll
            for (int b = 0; b < 2; b++) acc[a][b] = (f32x4)0.f;

        for (int kt = 0; kt < 12; kt++) {
            const int seg  = kt >> 2;
            const int kloc = (kt & 3) << 6;
            const u16* Ag = (seg == 1) ? Fl : Fh;
            const u16* Bg = (seg == 2) ? Fl : Fh;

            __syncthreads();
#pragma unroll
            for (int i = 0; i < 4; i++) {
                const int rbase = w * 32 + i * 8;
                GLOAD_LDS16(&Ag[(size_t)(i0 + rbase + srow) * NHID + kloc + acol],
                            smem + rbase * 128);
            }
#pragma unroll
            for (int i = 0; i < 2; i++) {
                const int rbase = (w + i * 4) * 8;
                GLOAD_LDS16(&Bg[(size_t)(jt + rbase + srow) * NHID + kloc + acol],
                            smem + 16384 + rbase * 128);
            }
            __syncthreads();

#pragma unroll
            for (int ks = 0; ks < 2; ks++) {
                const int slotx = ((ks * 4 + lg) ^ (lr & 7)) * 16;
                short8 av[2], bv[4];
#pragma unroll
                for (int fi = 0; fi < 2; fi++)
                    av[fi] = *(const short8*)(smem + (w * 32 + fi * 16 + lr) * 128 + slotx);
#pragma unroll
                for (int fj = 0; fj < 4; fj++)
                    bv[fj] = *(const short8*)(smem + 16384 + (fj * 16 + lr) * 128 + slotx);
#pragma unroll
                for (int fj = 0; fj < 4; fj++)
#pragma unroll
                    for (int fi = 0; fi < 2; fi++)
                        acc[fj][fi] = __builtin_amdgcn_mfma_f32_16x16x32_bf16(
                            bv[fj], av[fi], acc[fj][fi], 0, 0, 0);
            }
        }

        // dump C tile: row = w*32+fi*16+lr, cols fj*16+lg*4 .. +3
#pragma unroll
        for (int fj = 0; fj < 4; fj++)
#pragma unroll
            for (int fi = 0; fi < 2; fi++)
                *(f32x4*)&Cs[(w * 32 + fi * 16 + lr) * 68 + fj * 16 + lg * 4] = acc[fj][fi];
        __syncthreads();

        // merge: each thread scans its 32 cols of its row
#pragma unroll
        for (int q = 0; q < 8; q++) {
            f32x4 c4 = *(const f32x4*)&Cs[mrow * 68 + mhalf * 32 + q * 4];
            const int gbase = jt + mhalf * 32 + q * 4;
#pragma unroll
            for (int e = 0; e < 4; e++) {
                float val = c4[e];
                int gi = gbase + e;
                if (val > rm) { rl = rl * __expf(rm - val) + 1.f; rm = val; }
                else          { rl += __expf(val - rm); }
                ins8(val, gi, tv, ti);
            }
        }
        // Cs reuse next tile is safe: next tile's first kt barrier fences.
    }

    // pair-merge (lanes 2k <- 2k+1 via shfl_xor 1)
    float pm = __shfl_xor(rm, 1);
    float pl = __shfl_xor(rl, 1);
    float M2 = fmaxf(rm, pm);
    float L2 = rl * __expf(rm - M2) + pl * __expf(pm - M2);
#pragma unroll
    for (int s = 0; s < 8; s++) {
        float pv = __shfl_xor(tv[s], 1);
        int   pi = __shfl_xor(ti[s], 1);
        if (mhalf == 0) ins8(pv, pi, tv, ti);
    }
    if (mhalf == 0) {
        const int rec = ((i0 + mrow) << 3) + split;
        Ml[rec * 2]     = M2;
        Ml[rec * 2 + 1] = L2;
#pragma unroll
        for (int s = 0; s < 8; s++) {
            Vsp[rec * 8 + s] = tv[s];
            Isp[rec * 8 + s] = ti[s];
        }
    }
}

// =====================================================================
// K5: merge per-split records -> global top-8 + softmax normalize
// =====================================================================
__global__ __launch_bounds__(64) void merge_topk_kernel(
    const float* __restrict__ Ml, const float* __restrict__ Vsp,
    const int* __restrict__ Isp, float* __restrict__ topv, int* __restrict__ topi)
{
    const int row = blockIdx.x * 64 + threadIdx.x;
    const int rb = row * 8;

    float M = -INFINITY;
#pragma unroll
    for (int s = 0; s < 8; s++) M = fmaxf(M, Ml[(rb + s) * 2]);
    float L = 0.f;
#pragma unroll
    for (int s = 0; s < 8; s++)
        L += Ml[(rb + s) * 2 + 1] * __expf(Ml[(rb + s) * 2] - M);

    float tv[8]; int ti[8];
#pragma unroll
    for (int s = 0; s < 8; s++) { tv[s] = -INFINITY; ti[s] = 0x7fffffff; }
#pragma unroll
    for (int s = 0; s < 8; s++)
#pragma unroll
        for (int k = 0; k < 8; k++)
            ins8(Vsp[(rb + s) * 8 + k], Isp[(rb + s) * 8 + k], tv, ti);

    const float invL = 1.f / L;
#pragma unroll
    for (int k = 0; k < 8; k++) {
        topv[rb + k] = __expf(tv[k] - M) * invL;
        topi[rb + k] = ti[k];
    }
}

// =====================================================================
// K6: H = eye(B), nontemporal
// =====================================================================
__global__ __launch_bounds__(256) void hfill_kernel(float* __restrict__ H)
{
    size_t base = (size_t)blockIdx.x * 256 + threadIdx.x;
#pragma unroll
    for (int i = 0; i < 8; i++) {
        size_t id = base + (size_t)i * 2097152;
        size_t p = id * 4;
        int r = (int)(p >> 13);
        int c = (int)(p & 8191);
        f32x4 o;
        o[0] = (c == r)     ? 1.f : 0.f;
        o[1] = (c + 1 == r) ? 1.f : 0.f;
        o[2] = (c + 2 == r) ? 1.f : 0.f;
        o[3] = (c + 3 == r) ? 1.f : 0.f;
        __builtin_nontemporal_store(o, (f32x4*)&H[p]);
    }
}

// =====================================================================
// K7: scatter H[idx[i][r], i] = val[i][r]
// =====================================================================
__global__ __launch_bounds__(256) void scatter_kernel(
    const float* __restrict__ topv, const int* __restrict__ topi, float* __restrict__ H)
{
    int t = blockIdx.x * 256 + threadIdx.x;
    int i = t >> 3;
    H[(size_t)topi[t] * NB + i] = topv[t];
}

// =====================================================================
extern "C" void kernel_launch(void* const* d_in, const int* in_sizes, int n_in,
                              void* d_out, int out_size, void* d_ws, size_t ws_size,
                              hipStream_t stream)
{
    const float* x0  = (const float*)d_in[0];
    const float* Wp0 = (const float*)d_in[1];
    const float* bp0 = (const float*)d_in[2];
    const float* g0  = (const float*)d_in[3];
    const float* be0 = (const float*)d_in[4];
    const float* x1  = (const float*)d_in[5];
    const float* Wp1 = (const float*)d_in[6];
    const float* bp1 = (const float*)d_in[7];
    const float* g1  = (const float*)d_in[8];
    const float* be1 = (const float*)d_in[9];
    const float* x2  = (const float*)d_in[10];
    const float* Wp2 = (const float*)d_in[11];
    const float* bp2 = (const float*)d_in[12];
    const float* g2  = (const float*)d_in[13];
    const float* be2 = (const float*)d_in[14];
    const float* Win = (const float*)d_in[15];
    const float* bin = (const float*)d_in[16];
    const float* Wout= (const float*)d_in[17];
    const float* bout= (const float*)d_in[18];
    const float* W1  = (const float*)d_in[19];
    const float* b1  = (const float*)d_in[20];
    const float* W2  = (const float*)d_in[21];
    const float* b2  = (const float*)d_in[22];

    float* out = (float*)d_out;
    char*  outc = (char*)d_out;

    // scratch inside d_out (all dead before hfill's eye overwrite;
    // split records are consumed by merge BEFORE hfill runs):
    float* qkv   = out;                              // [0, 75497472)
    u16*   seqh  = (u16*)(outc + 75497472);          // 12.6 MB
    u16*   seql  = (u16*)(outc + 88080384);          // 12.6 MB
    u16*   WTh   = (u16*)(outc + 100663296);         // 1.18 MB
    u16*   WTl   = (u16*)(outc + 101842944);         // 1.18 MB
    u16*   WinTh = (u16*)(outc + 103022592);         // 384 KB
    u16*   WinTl = (u16*)(outc + 103415808);         // 384 KB (ends 103809024)
    float* Ml    = (float*)(outc + 104857600);       // 8192x8x2  = 512 KB
    float* Vsp   = (float*)(outc + 105906176);       // 8192x8x8  = 2 MB
    int*   Isp   = (int*)(outc + 108003328);         // 8192x8x8  = 2 MB (ends 110100480)
    // persistent scratch in d_ws (8.5 MB):
    u16*   Fh   = (u16*)d_ws;
    u16*   Fl   = (u16*)((char*)d_ws + (4u << 20));
    float* topv = (float*)((char*)d_ws + (8u << 20));
    int*   topi = (int*)((char*)d_ws + (8u << 20) + 262144);
    float* ew   = out + (size_t)NB * NB;

    wconv_kernel<<<768, 256, 0, stream>>>(Wp0, Wp1, Wp2, Win, WTh, WTl, WinTh, WinTl);
    proj_mfma_kernel<<<dim3(128, 3), 256, 0, stream>>>(
        x0, x1, x2, bp0, g0, be0, bp1, g1, be1, bp2, g2, be2, WTh, WTl, seqh, seql);
    qkv_mfma_kernel<<<dim3(3, 384), 256, 0, stream>>>(seqh, seql, WinTh, WinTl, bin, qkv);
    attn_kernel<<<2048, 256, 0, stream>>>(qkv, Wout, bout, W1, b1, W2, b2, Fh, Fl, ew);
    fused_sim_topk_kernel<<<512, 256, 0, stream>>>(Fh, Fl, Ml, Vsp, Isp);
    merge_topk_kernel<<<128, 64, 0, stream>>>(Ml, Vsp, Isp, topv, topi);
    hfill_kernel<<<8192, 256, 0, stream>>>(out);
    scatter_kernel<<<256, 256, 0, stream>>>(topv, topi, out);
}